// Round 4
// baseline (400.104 us; speedup 1.0000x reference)
//
#include <hip/hip_runtime.h>
#include <hip/hip_bf16.h>
#include <math.h>

// Problem dims (fixed by reference)
#define BB 64
#define SS 200
#define TT 32
#define EE 128
#define CC 128
#define HH 100
#define G3 300           // 3*H
#define OUTD 104
#define NTREE (BB*SS)    // 12800

typedef __attribute__((ext_vector_type(8))) short short8;
typedef __attribute__((ext_vector_type(4))) float f32x4;

__device__ inline unsigned short f2bf_rne(float f) {
    union { float f; unsigned u; } x; x.f = f;
    unsigned r = (x.u + 0x7FFFu + ((x.u >> 16) & 1u)) >> 16;
    return (unsigned short)r;
}
__device__ inline float bf2f(unsigned short h) {
    union { unsigned u; float f; } x; x.u = ((unsigned)h) << 16;
    return x.f;
}
__device__ inline float fast_sigmoid(float x) {
    return __builtin_amdgcn_rcpf(1.f + __builtin_amdgcn_exp2f(-1.4426950408889634f * x));
}
__device__ inline float fast_tanh(float x) {
    // tanh(x) = 1 - 2/(1 + e^{2x}); exp2 saturates correctly at +/-inf
    return 1.f - 2.f * __builtin_amdgcn_rcpf(1.f + __builtin_amdgcn_exp2f(2.8853900817779268f * x));
}

// ---------------- K1 (MFMA): embed-gather -> bf16 GEMM vs W_lin^T -> bias -> tree-sum -> maxpool
#define K1_TPI 2
#define AROWS (K1_TPI*TT)        // 64
#define LDA 136                  // bf16/row: 128 + 8 pad
#define LDC 132                  // fp32/row: 128 + 4 pad

__global__ __launch_bounds__(256) void k1_mfma(const int* __restrict__ tok,
                                               const float* __restrict__ emb,
                                               const float* __restrict__ w_lin,
                                               const float* __restrict__ b_lin,
                                               float* __restrict__ tree_vec) {
    __shared__ __align__(16) unsigned short A_sh[AROWS * LDA];   // 17408 B
    __shared__ __align__(16) float C_sh[AROWS * LDC];            // 33792 B
    __shared__ int tok_sh[AROWS];

    const int tid  = threadIdx.x;
    const int wave = tid >> 6;
    const int lane = tid & 63;
    const int r = lane & 15;
    const int q = lane >> 4;

    short8 bfrag[2][4];
    float  bias[2];
#pragma unroll
    for (int nt = 0; nt < 2; ++nt) {
        const int n = wave * 32 + nt * 16 + r;
        bias[nt] = b_lin[n];
#pragma unroll
        for (int kt = 0; kt < 4; ++kt) {
            const float* src = w_lin + (long)n * EE + kt * 32 + q * 8;
            float4 a = ((const float4*)src)[0];
            float4 b = ((const float4*)src)[1];
            short8 f;
            f[0] = (short)f2bf_rne(a.x); f[1] = (short)f2bf_rne(a.y);
            f[2] = (short)f2bf_rne(a.z); f[3] = (short)f2bf_rne(a.w);
            f[4] = (short)f2bf_rne(b.x); f[5] = (short)f2bf_rne(b.y);
            f[6] = (short)f2bf_rne(b.z); f[7] = (short)f2bf_rne(b.w);
            bfrag[nt][kt] = f;
        }
    }

    const int tree0 = blockIdx.x * K1_TPI;
    if (tid < AROWS) tok_sh[tid] = tok[tree0 * TT + tid];
    __syncthreads();

#pragma unroll
    for (int i = 0; i < 8; ++i) {
        const int idx = tid + i * 256;
        const int row = idx >> 5;
        const int p   = idx & 31;
        const float4 e = ((const float4*)(emb + (long)tok_sh[row] * EE))[p];
        unsigned short* dst = &A_sh[row * LDA + p * 4];
        dst[0] = f2bf_rne(e.x); dst[1] = f2bf_rne(e.y);
        dst[2] = f2bf_rne(e.z); dst[3] = f2bf_rne(e.w);
    }
    __syncthreads();

    f32x4 acc[4][2];
#pragma unroll
    for (int mt = 0; mt < 4; ++mt)
#pragma unroll
        for (int nt = 0; nt < 2; ++nt) acc[mt][nt] = (f32x4)(0.f);

#pragma unroll
    for (int mt = 0; mt < 4; ++mt) {
        const int m = mt * 16 + r;
        short8 afrag[4];
#pragma unroll
        for (int kt = 0; kt < 4; ++kt)
            afrag[kt] = *(const short8*)&A_sh[m * LDA + kt * 32 + q * 8];
#pragma unroll
        for (int nt = 0; nt < 2; ++nt)
#pragma unroll
            for (int kt = 0; kt < 4; ++kt)
                acc[mt][nt] = __builtin_amdgcn_mfma_f32_16x16x32_bf16(
                    afrag[kt], bfrag[nt][kt], acc[mt][nt], 0, 0, 0);
    }

#pragma unroll
    for (int mt = 0; mt < 4; ++mt)
#pragma unroll
        for (int nt = 0; nt < 2; ++nt) {
            const int col = wave * 32 + nt * 16 + r;
#pragma unroll
            for (int reg = 0; reg < 4; ++reg) {
                const int row = mt * 16 + q * 4 + reg;
                C_sh[row * LDC + col] = acc[mt][nt][reg] + bias[nt];
            }
        }
    __syncthreads();

    {
        const int t = tid >> 7;
        const int j = tid & 127;
        float* base = &C_sh[(t * TT) * LDC + j];
        for (int n = TT - 1; n >= 1; --n)
            base[((n - 1) >> 1) * LDC] += base[n * LDC];
        float m = base[0];
#pragma unroll
        for (int n = 1; n < TT; ++n) m = fmaxf(m, base[n * LDC]);
        tree_vec[(long)(tree0 + t) * CC + j] = m;
    }
}

// ---------------- K2 (MFMA, hi/lo split): gx[dir][m=b*S+s][300] = X @ W_ih^T + b_ih
#define K2_NPAD 320
__global__ __launch_bounds__(256) void k2_mfma(const float* __restrict__ tree_vec,
                                               const float* __restrict__ w_ih_f,
                                               const float* __restrict__ b_ih_f,
                                               const float* __restrict__ w_ih_b,
                                               const float* __restrict__ b_ih_b,
                                               float* __restrict__ gx) {
    __shared__ __align__(16) unsigned short Ahi[32 * LDA];
    __shared__ __align__(16) unsigned short Alo[32 * LDA];
    __shared__ __align__(16) unsigned short Bhi[64 * LDA];
    __shared__ __align__(16) unsigned short Blo[64 * LDA];

    const int tid  = threadIdx.x;
    const int wave = tid >> 6;
    const int lane = tid & 63;
    const int r = lane & 15;
    const int q = lane >> 4;

    const int nb = blockIdx.x % 10;
    const int mb = blockIdx.x / 10;
    const int m0 = mb * 32;
    const int n0 = nb * 64;

#pragma unroll
    for (int i = 0; i < 4; ++i) {
        const int idx = tid + i * 256;
        const int row = idx >> 5;
        const int p   = idx & 31;
        const float4 v = ((const float4*)(tree_vec + (long)(m0 + row) * CC))[p];
        unsigned short* dh = &Ahi[row * LDA + p * 4];
        unsigned short* dl = &Alo[row * LDA + p * 4];
        float e[4] = {v.x, v.y, v.z, v.w};
#pragma unroll
        for (int c = 0; c < 4; ++c) {
            unsigned short h = f2bf_rne(e[c]);
            dh[c] = h;
            dl[c] = f2bf_rne(e[c] - bf2f(h));
        }
    }
#pragma unroll
    for (int i = 0; i < 8; ++i) {
        const int idx = tid + i * 256;
        const int row = idx >> 5;
        const int p   = idx & 31;
        const int n   = n0 + row;
        const int dir = (n >= K2_NPAD) ? 1 : 0;
        const int j   = n - dir * K2_NPAD;
        const int jj  = (j < G3) ? j : 0;
        const float* w = dir ? w_ih_b : w_ih_f;
        const float4 v = ((const float4*)(w + (long)jj * EE))[p];
        unsigned short* dh = &Bhi[row * LDA + p * 4];
        unsigned short* dl = &Blo[row * LDA + p * 4];
        float e[4] = {v.x, v.y, v.z, v.w};
#pragma unroll
        for (int c = 0; c < 4; ++c) {
            unsigned short h = f2bf_rne(e[c]);
            dh[c] = h;
            dl[c] = f2bf_rne(e[c] - bf2f(h));
        }
    }
    __syncthreads();

    const int nloc = wave * 16 + r;
    short8 bh[4], bl[4];
#pragma unroll
    for (int kt = 0; kt < 4; ++kt) {
        bh[kt] = *(const short8*)&Bhi[nloc * LDA + kt * 32 + q * 8];
        bl[kt] = *(const short8*)&Blo[nloc * LDA + kt * 32 + q * 8];
    }

    f32x4 acc[2];
    acc[0] = (f32x4)(0.f); acc[1] = (f32x4)(0.f);
#pragma unroll
    for (int mt = 0; mt < 2; ++mt) {
        const int m = mt * 16 + r;
#pragma unroll
        for (int kt = 0; kt < 4; ++kt) {
            short8 ah = *(const short8*)&Ahi[m * LDA + kt * 32 + q * 8];
            short8 al = *(const short8*)&Alo[m * LDA + kt * 32 + q * 8];
            acc[mt] = __builtin_amdgcn_mfma_f32_16x16x32_bf16(ah, bh[kt], acc[mt], 0, 0, 0);
            acc[mt] = __builtin_amdgcn_mfma_f32_16x16x32_bf16(ah, bl[kt], acc[mt], 0, 0, 0);
            acc[mt] = __builtin_amdgcn_mfma_f32_16x16x32_bf16(al, bh[kt], acc[mt], 0, 0, 0);
        }
    }

    const int ng  = n0 + wave * 16 + r;
    const int dir = (ng >= K2_NPAD) ? 1 : 0;
    const int j   = ng - dir * K2_NPAD;
    const bool valid = (j < G3);
    const float bias = valid ? (dir ? b_ih_b[j] : b_ih_f[j]) : 0.f;
    float* gxd = gx + (long)dir * NTREE * G3;
    if (valid) {
#pragma unroll
        for (int mt = 0; mt < 2; ++mt)
#pragma unroll
            for (int reg = 0; reg < 4; ++reg) {
                const int m = m0 + mt * 16 + q * 4 + reg;
                gxd[(long)m * G3 + j] = acc[mt][reg] + bias;
            }
    }
}

// ---------------- K3 (MFMA matvec): GRU recurrence, one block (4 waves) per (batch, dir)
// gh[300] = W_hh . h via 16x16x32 bf16 MFMA (row 0 only), W_hh persistent in registers
// as hi/lo fragments (3-term split ~ fp32). h carried in fp32 regs; bf16 hi/lo via LDS.
#define K3_NT 19
__global__ __launch_bounds__(256, 1) void k3_gru(const float* __restrict__ gx,
                                                 const float* __restrict__ w_hh_f,
                                                 const float* __restrict__ b_hh_f,
                                                 const float* __restrict__ w_hh_b,
                                                 const float* __restrict__ b_hh_b,
                                                 float* __restrict__ pool) {
    const int bid = blockIdx.x;   // 0..127
    const int dir = bid & 1;
    const int b = bid >> 1;
    const float* w_hh = dir ? w_hh_b : w_hh_f;
    const float* b_hh = dir ? b_hh_b : b_hh_f;

    __shared__ __align__(16) unsigned short hhi_sh[128];   // bf16 h (hi), k-padded with 0
    __shared__ __align__(16) unsigned short hlo_sh[128];   // bf16 h (lo)
    __shared__ float gates_sh[G3 + 4];

    const int tid  = threadIdx.x;
    const int wave = tid >> 6;
    const int lane = tid & 63;
    const int r = lane & 15;
    const int q = lane >> 4;

    // ---- persistent B fragments: B[k][n] = W_hh[n][k]; lane(r,q) holds k=kt*32+q*8..+7, n=tile*16+r
    short8 bhi[5][4], blo[5][4];
    float  bias[5];
#pragma unroll
    for (int i = 0; i < 5; ++i) {
        const int ntg = wave * 5 + i;
        const int n = ntg * 16 + r;
        const bool nv = (ntg < K3_NT) && (n < G3);
        bias[i] = nv ? b_hh[n] : 0.f;
#pragma unroll
        for (int kt = 0; kt < 4; ++kt) {
            short8 h8, l8;
#pragma unroll
            for (int e = 0; e < 8; ++e) {
                const int k = kt * 32 + q * 8 + e;
                const float v = (nv && k < HH) ? w_hh[n * HH + k] : 0.f;
                const unsigned short hb = f2bf_rne(v);
                h8[e] = (short)hb;
                l8[e] = (short)f2bf_rne(v - bf2f(hb));
            }
            bhi[i][kt] = h8;
            blo[i][kt] = l8;
        }
    }

    if (tid < 128) { hhi_sh[tid] = 0; hlo_sh[tid] = 0; }

    const float* gxd = gx + (long)dir * NTREE * G3;
    const int sstep = dir ? -1 : 1;
    int s = dir ? (SS - 1) : 0;
    const int j = tid;
    float xr = 0.f, xz = 0.f, xn = 0.f;
    if (j < HH) {
        const long base = ((long)b * SS + s) * G3;
        xr = gxd[base + j];
        xz = gxd[base + HH + j];
        xn = gxd[base + 2 * HH + j];
    }
    float hj = 0.f, hmax = -1e30f;
    __syncthreads();

    for (int t = 0; t < SS; ++t) {
        // ---- phase 1: gh = W_hh . h (+b_hh) -> gates_sh (MFMA row 0)
        short8 ahi[4], alo[4];
#pragma unroll
        for (int kt = 0; kt < 4; ++kt) {
            ahi[kt] = *(const short8*)&hhi_sh[kt * 32 + q * 8];   // broadcast read
            alo[kt] = *(const short8*)&hlo_sh[kt * 32 + q * 8];
        }
#pragma unroll
        for (int i = 0; i < 5; ++i) {
            const int ntg = wave * 5 + i;
            if (ntg < K3_NT) {
                f32x4 acc = (f32x4)(0.f);
#pragma unroll
                for (int kt = 0; kt < 4; ++kt) {
                    acc = __builtin_amdgcn_mfma_f32_16x16x32_bf16(ahi[kt], bhi[i][kt], acc, 0, 0, 0);
                    acc = __builtin_amdgcn_mfma_f32_16x16x32_bf16(alo[kt], bhi[i][kt], acc, 0, 0, 0);
                    acc = __builtin_amdgcn_mfma_f32_16x16x32_bf16(ahi[kt], blo[i][kt], acc, 0, 0, 0);
                }
                const int n = ntg * 16 + r;
                if (lane < 16 && n < G3)               // C row0 = lanes 0..15, reg 0
                    gates_sh[n] = acc[0] + bias[i];
            }
        }
        __syncthreads();

        // ---- phase 2: activations + h update (threads j<100)
        const int s_n = s + sstep;
        if (j < HH) {
            float xr_n = 0.f, xz_n = 0.f, xn_n = 0.f;
            if (t < SS - 1) {                           // prefetch next step's gx
                const long base = ((long)b * SS + s_n) * G3;
                xr_n = gxd[base + j];
                xz_n = gxd[base + HH + j];
                xn_n = gxd[base + 2 * HH + j];
            }
            const float ghr = gates_sh[j];
            const float ghz = gates_sh[HH + j];
            const float ghn = gates_sh[2 * HH + j];
            const float rg = fast_sigmoid(xr + ghr);
            const float zg = fast_sigmoid(xz + ghz);
            const float ng = fast_tanh(xn + rg * ghn);
            hj = (1.f - zg) * ng + zg * hj;
            hmax = fmaxf(hmax, hj);
            const unsigned short hb = f2bf_rne(hj);
            hhi_sh[j] = hb;
            hlo_sh[j] = f2bf_rne(hj - bf2f(hb));
            xr = xr_n; xz = xz_n; xn = xn_n;
        }
        __syncthreads();
        s = s_n;
    }
    if (j < HH) pool[(long)b * (2 * HH) + dir * HH + j] = hmax;
}

// ---------------- K4: out[b][o] = fc_b[o] + pool[b,:] . fc_w[o,:]
__global__ __launch_bounds__(256) void k4_fc(const float* __restrict__ pool,
                                             const float* __restrict__ fc_w,
                                             const float* __restrict__ fc_b,
                                             float* __restrict__ out) {
    const int b = blockIdx.x;
    __shared__ __align__(16) float p_sh[2 * HH];
    const int t = threadIdx.x;
    if (t < 2 * HH) p_sh[t] = pool[(long)b * (2 * HH) + t];
    __syncthreads();
    if (t < OUTD) {
        const float4* wr4 = (const float4*)(fc_w + (long)t * (2 * HH));
        const float4* p4 = (const float4*)p_sh;
        float a0 = 0.f, a1 = 0.f;
#pragma unroll
        for (int k = 0; k < 50; k += 2) {
            float4 w0 = wr4[k],   p0 = p4[k];
            float4 w1 = wr4[k+1], p1 = p4[k+1];
            a0 += w0.x*p0.x + w0.y*p0.y + w0.z*p0.z + w0.w*p0.w;
            a1 += w1.x*p1.x + w1.y*p1.y + w1.z*p1.z + w1.w*p1.w;
        }
        out[(long)b * OUTD + t] = fc_b[t] + a0 + a1;
    }
}

extern "C" void kernel_launch(void* const* d_in, const int* in_sizes, int n_in,
                              void* d_out, int out_size, void* d_ws, size_t ws_size,
                              hipStream_t stream) {
    const int*   tok    = (const int*)d_in[0];
    const float* emb    = (const float*)d_in[4];
    const float* w_lin  = (const float*)d_in[5];
    const float* b_lin  = (const float*)d_in[6];
    const float* w_ih_f = (const float*)d_in[7];
    const float* w_hh_f = (const float*)d_in[8];
    const float* b_ih_f = (const float*)d_in[9];
    const float* b_hh_f = (const float*)d_in[10];
    const float* w_ih_b = (const float*)d_in[11];
    const float* w_hh_b = (const float*)d_in[12];
    const float* b_ih_b = (const float*)d_in[13];
    const float* b_hh_b = (const float*)d_in[14];
    const float* fc_w   = (const float*)d_in[15];
    const float* fc_b   = (const float*)d_in[16];

    float* ws       = (float*)d_ws;
    float* tree_vec = ws;                                   // 12800*128
    float* gx       = tree_vec + (long)NTREE * CC;          // 2*12800*300
    float* pool     = gx + (long)2 * NTREE * G3;            // 64*200
    float* out      = (float*)d_out;

    k1_mfma<<<NTREE / K1_TPI, 256, 0, stream>>>(tok, emb, w_lin, b_lin, tree_vec);
    k2_mfma<<<(NTREE / 32) * 10, 256, 0, stream>>>(tree_vec, w_ih_f, b_ih_f, w_ih_b, b_ih_b, gx);
    k3_gru <<<2 * BB, 256, 0, stream>>>(gx, w_hh_f, b_hh_f, w_hh_b, b_hh_b, pool);
    k4_fc  <<<BB, 256, 0, stream>>>(pool, fc_w, fc_b, out);
}

// Round 5
// 372.927 us; speedup vs baseline: 1.0729x; 1.0729x over previous
//
#include <hip/hip_runtime.h>
#include <hip/hip_bf16.h>
#include <math.h>

// Problem dims (fixed by reference)
#define BB 64
#define SS 200
#define TT 32
#define EE 128
#define CC 128
#define HH 100
#define G3 300           // 3*H
#define OUTD 104
#define NTREE (BB*SS)    // 12800

typedef __attribute__((ext_vector_type(8))) short short8;
typedef __attribute__((ext_vector_type(4))) float f32x4;

__device__ inline unsigned short f2bf_rne(float f) {
    union { float f; unsigned u; } x; x.f = f;
    unsigned r = (x.u + 0x7FFFu + ((x.u >> 16) & 1u)) >> 16;
    return (unsigned short)r;
}
__device__ inline float bf2f(unsigned short h) {
    union { unsigned u; float f; } x; x.u = ((unsigned)h) << 16;
    return x.f;
}
__device__ inline float fast_sigmoid(float x) {
    return __builtin_amdgcn_rcpf(1.f + __builtin_amdgcn_exp2f(-1.4426950408889634f * x));
}
__device__ inline float fast_tanh(float x) {
    return 1.f - 2.f * __builtin_amdgcn_rcpf(1.f + __builtin_amdgcn_exp2f(2.8853900817779268f * x));
}

// ---------------- K1 (MFMA): embed-gather -> bf16 GEMM vs W_lin^T -> bias -> tree-sum -> maxpool
#define K1_TPI 2
#define AROWS (K1_TPI*TT)        // 64
#define LDA 136                  // bf16/row: 128 + 8 pad
#define LDC 132                  // fp32/row: 128 + 4 pad

__global__ __launch_bounds__(256) void k1_mfma(const int* __restrict__ tok,
                                               const float* __restrict__ emb,
                                               const float* __restrict__ w_lin,
                                               const float* __restrict__ b_lin,
                                               float* __restrict__ tree_vec) {
    __shared__ __align__(16) unsigned short A_sh[AROWS * LDA];   // 17408 B
    __shared__ __align__(16) float C_sh[AROWS * LDC];            // 33792 B
    __shared__ int tok_sh[AROWS];

    const int tid  = threadIdx.x;
    const int wave = tid >> 6;
    const int lane = tid & 63;
    const int r = lane & 15;
    const int q = lane >> 4;

    short8 bfrag[2][4];
    float  bias[2];
#pragma unroll
    for (int nt = 0; nt < 2; ++nt) {
        const int n = wave * 32 + nt * 16 + r;
        bias[nt] = b_lin[n];
#pragma unroll
        for (int kt = 0; kt < 4; ++kt) {
            const float* src = w_lin + (long)n * EE + kt * 32 + q * 8;
            float4 a = ((const float4*)src)[0];
            float4 b = ((const float4*)src)[1];
            short8 f;
            f[0] = (short)f2bf_rne(a.x); f[1] = (short)f2bf_rne(a.y);
            f[2] = (short)f2bf_rne(a.z); f[3] = (short)f2bf_rne(a.w);
            f[4] = (short)f2bf_rne(b.x); f[5] = (short)f2bf_rne(b.y);
            f[6] = (short)f2bf_rne(b.z); f[7] = (short)f2bf_rne(b.w);
            bfrag[nt][kt] = f;
        }
    }

    const int tree0 = blockIdx.x * K1_TPI;
    if (tid < AROWS) tok_sh[tid] = tok[tree0 * TT + tid];
    __syncthreads();

#pragma unroll
    for (int i = 0; i < 8; ++i) {
        const int idx = tid + i * 256;
        const int row = idx >> 5;
        const int p   = idx & 31;
        const float4 e = ((const float4*)(emb + (long)tok_sh[row] * EE))[p];
        unsigned short* dst = &A_sh[row * LDA + p * 4];
        dst[0] = f2bf_rne(e.x); dst[1] = f2bf_rne(e.y);
        dst[2] = f2bf_rne(e.z); dst[3] = f2bf_rne(e.w);
    }
    __syncthreads();

    f32x4 acc[4][2];
#pragma unroll
    for (int mt = 0; mt < 4; ++mt)
#pragma unroll
        for (int nt = 0; nt < 2; ++nt) acc[mt][nt] = (f32x4)(0.f);

#pragma unroll
    for (int mt = 0; mt < 4; ++mt) {
        const int m = mt * 16 + r;
        short8 afrag[4];
#pragma unroll
        for (int kt = 0; kt < 4; ++kt)
            afrag[kt] = *(const short8*)&A_sh[m * LDA + kt * 32 + q * 8];
#pragma unroll
        for (int nt = 0; nt < 2; ++nt)
#pragma unroll
            for (int kt = 0; kt < 4; ++kt)
                acc[mt][nt] = __builtin_amdgcn_mfma_f32_16x16x32_bf16(
                    afrag[kt], bfrag[nt][kt], acc[mt][nt], 0, 0, 0);
    }

#pragma unroll
    for (int mt = 0; mt < 4; ++mt)
#pragma unroll
        for (int nt = 0; nt < 2; ++nt) {
            const int col = wave * 32 + nt * 16 + r;
#pragma unroll
            for (int reg = 0; reg < 4; ++reg) {
                const int row = mt * 16 + q * 4 + reg;
                C_sh[row * LDC + col] = acc[mt][nt][reg] + bias[nt];
            }
        }
    __syncthreads();

    // ---- tree-sum + maxpool fully in registers (no serial LDS RMW chain).
    // Descending n: when n is processed, its children (2n+1,2n+2 > n) already
    // folded in, so v[n] IS the subtree sum -> max then add to parent.
    {
        const int t = tid >> 7;
        const int j = tid & 127;
        const float* base = &C_sh[(t * TT) * LDC + j];
        float v[TT];
#pragma unroll
        for (int n = 0; n < TT; ++n) v[n] = base[n * LDC];
        float m = -1e30f;
#pragma unroll
        for (int n = TT - 1; n >= 1; --n) {
            m = fmaxf(m, v[n]);
            v[(n - 1) >> 1] += v[n];
        }
        m = fmaxf(m, v[0]);
        tree_vec[(long)(tree0 + t) * CC + j] = m;
    }
}

// ---------------- K2 (MFMA, hi/lo split): gx[dir][m=b*S+s][300] = X @ W_ih^T + b_ih
#define K2_NPAD 320
__global__ __launch_bounds__(256) void k2_mfma(const float* __restrict__ tree_vec,
                                               const float* __restrict__ w_ih_f,
                                               const float* __restrict__ b_ih_f,
                                               const float* __restrict__ w_ih_b,
                                               const float* __restrict__ b_ih_b,
                                               float* __restrict__ gx) {
    __shared__ __align__(16) unsigned short Ahi[32 * LDA];
    __shared__ __align__(16) unsigned short Alo[32 * LDA];
    __shared__ __align__(16) unsigned short Bhi[64 * LDA];
    __shared__ __align__(16) unsigned short Blo[64 * LDA];

    const int tid  = threadIdx.x;
    const int wave = tid >> 6;
    const int lane = tid & 63;
    const int r = lane & 15;
    const int q = lane >> 4;

    const int nb = blockIdx.x % 10;
    const int mb = blockIdx.x / 10;
    const int m0 = mb * 32;
    const int n0 = nb * 64;

#pragma unroll
    for (int i = 0; i < 4; ++i) {
        const int idx = tid + i * 256;
        const int row = idx >> 5;
        const int p   = idx & 31;
        const float4 v = ((const float4*)(tree_vec + (long)(m0 + row) * CC))[p];
        unsigned short* dh = &Ahi[row * LDA + p * 4];
        unsigned short* dl = &Alo[row * LDA + p * 4];
        float e[4] = {v.x, v.y, v.z, v.w};
#pragma unroll
        for (int c = 0; c < 4; ++c) {
            unsigned short h = f2bf_rne(e[c]);
            dh[c] = h;
            dl[c] = f2bf_rne(e[c] - bf2f(h));
        }
    }
#pragma unroll
    for (int i = 0; i < 8; ++i) {
        const int idx = tid + i * 256;
        const int row = idx >> 5;
        const int p   = idx & 31;
        const int n   = n0 + row;
        const int dir = (n >= K2_NPAD) ? 1 : 0;
        const int j   = n - dir * K2_NPAD;
        const int jj  = (j < G3) ? j : 0;
        const float* w = dir ? w_ih_b : w_ih_f;
        const float4 v = ((const float4*)(w + (long)jj * EE))[p];
        unsigned short* dh = &Bhi[row * LDA + p * 4];
        unsigned short* dl = &Blo[row * LDA + p * 4];
        float e[4] = {v.x, v.y, v.z, v.w};
#pragma unroll
        for (int c = 0; c < 4; ++c) {
            unsigned short h = f2bf_rne(e[c]);
            dh[c] = h;
            dl[c] = f2bf_rne(e[c] - bf2f(h));
        }
    }
    __syncthreads();

    const int nloc = wave * 16 + r;
    short8 bh[4], bl[4];
#pragma unroll
    for (int kt = 0; kt < 4; ++kt) {
        bh[kt] = *(const short8*)&Bhi[nloc * LDA + kt * 32 + q * 8];
        bl[kt] = *(const short8*)&Blo[nloc * LDA + kt * 32 + q * 8];
    }

    f32x4 acc[2];
    acc[0] = (f32x4)(0.f); acc[1] = (f32x4)(0.f);
#pragma unroll
    for (int mt = 0; mt < 2; ++mt) {
        const int m = mt * 16 + r;
#pragma unroll
        for (int kt = 0; kt < 4; ++kt) {
            short8 ah = *(const short8*)&Ahi[m * LDA + kt * 32 + q * 8];
            short8 al = *(const short8*)&Alo[m * LDA + kt * 32 + q * 8];
            acc[mt] = __builtin_amdgcn_mfma_f32_16x16x32_bf16(ah, bh[kt], acc[mt], 0, 0, 0);
            acc[mt] = __builtin_amdgcn_mfma_f32_16x16x32_bf16(ah, bl[kt], acc[mt], 0, 0, 0);
            acc[mt] = __builtin_amdgcn_mfma_f32_16x16x32_bf16(al, bh[kt], acc[mt], 0, 0, 0);
        }
    }

    const int ng  = n0 + wave * 16 + r;
    const int dir = (ng >= K2_NPAD) ? 1 : 0;
    const int j   = ng - dir * K2_NPAD;
    const bool valid = (j < G3);
    const float bias = valid ? (dir ? b_ih_b[j] : b_ih_f[j]) : 0.f;
    float* gxd = gx + (long)dir * NTREE * G3;
    if (valid) {
#pragma unroll
        for (int mt = 0; mt < 2; ++mt)
#pragma unroll
            for (int reg = 0; reg < 4; ++reg) {
                const int m = m0 + mt * 16 + q * 4 + reg;
                gxd[(long)m * G3 + j] = acc[mt][reg] + bias;
            }
    }
}

// ---------------- K3 (MFMA matvec): GRU recurrence, one block (4 waves) per (batch, dir)
// v3: 3 independent accumulator chains (depth 4, not 12) + prefetch hoisted to
// the top of phase 1 so MFMA+barrier+activations hide the gx load latency.
#define K3_NT 19
__global__ __launch_bounds__(256, 1) void k3_gru(const float* __restrict__ gx,
                                                 const float* __restrict__ w_hh_f,
                                                 const float* __restrict__ b_hh_f,
                                                 const float* __restrict__ w_hh_b,
                                                 const float* __restrict__ b_hh_b,
                                                 float* __restrict__ pool) {
    const int bid = blockIdx.x;   // 0..127
    const int dir = bid & 1;
    const int b = bid >> 1;
    const float* w_hh = dir ? w_hh_b : w_hh_f;
    const float* b_hh = dir ? b_hh_b : b_hh_f;

    __shared__ __align__(16) unsigned short hhi_sh[128];
    __shared__ __align__(16) unsigned short hlo_sh[128];
    __shared__ float gates_sh[G3 + 4];

    const int tid  = threadIdx.x;
    const int wave = tid >> 6;
    const int lane = tid & 63;
    const int r = lane & 15;
    const int q = lane >> 4;

    short8 bhi[5][4], blo[5][4];
    float  bias[5];
#pragma unroll
    for (int i = 0; i < 5; ++i) {
        const int ntg = wave * 5 + i;
        const int n = ntg * 16 + r;
        const bool nv = (ntg < K3_NT) && (n < G3);
        bias[i] = nv ? b_hh[n] : 0.f;
#pragma unroll
        for (int kt = 0; kt < 4; ++kt) {
            short8 h8, l8;
#pragma unroll
            for (int e = 0; e < 8; ++e) {
                const int k = kt * 32 + q * 8 + e;
                const float v = (nv && k < HH) ? w_hh[n * HH + k] : 0.f;
                const unsigned short hb = f2bf_rne(v);
                h8[e] = (short)hb;
                l8[e] = (short)f2bf_rne(v - bf2f(hb));
            }
            bhi[i][kt] = h8;
            blo[i][kt] = l8;
        }
    }

    if (tid < 128) { hhi_sh[tid] = 0; hlo_sh[tid] = 0; }

    const float* gxd = gx + (long)dir * NTREE * G3;
    const int sstep = dir ? -1 : 1;
    int s = dir ? (SS - 1) : 0;
    const int j = tid;
    float xr = 0.f, xz = 0.f, xn = 0.f;
    if (j < HH) {
        const long base = ((long)b * SS + s) * G3;
        xr = gxd[base + j];
        xz = gxd[base + HH + j];
        xn = gxd[base + 2 * HH + j];
    }
    float hj = 0.f, hmax = -1e30f;
    __syncthreads();

    for (int t = 0; t < SS; ++t) {
        // ---- prefetch next step's gx FIRST (covered by MFMA + barrier + activations)
        const int s_n = s + sstep;
        float xr_n = 0.f, xz_n = 0.f, xn_n = 0.f;
        if (t < SS - 1 && j < HH) {
            const long base = ((long)b * SS + s_n) * G3;
            xr_n = gxd[base + j];
            xz_n = gxd[base + HH + j];
            xn_n = gxd[base + 2 * HH + j];
        }

        // ---- phase 1: gh = W_hh . h (+b_hh) -> gates_sh
        short8 ahi[4], alo[4];
#pragma unroll
        for (int kt = 0; kt < 4; ++kt) {
            ahi[kt] = *(const short8*)&hhi_sh[kt * 32 + q * 8];
            alo[kt] = *(const short8*)&hlo_sh[kt * 32 + q * 8];
        }
#pragma unroll
        for (int i = 0; i < 5; ++i) {
            const int ntg = wave * 5 + i;
            if (ntg < K3_NT) {
                f32x4 a0 = (f32x4)(0.f), a1 = (f32x4)(0.f), a2 = (f32x4)(0.f);
#pragma unroll
                for (int kt = 0; kt < 4; ++kt) {
                    a0 = __builtin_amdgcn_mfma_f32_16x16x32_bf16(ahi[kt], bhi[i][kt], a0, 0, 0, 0);
                    a1 = __builtin_amdgcn_mfma_f32_16x16x32_bf16(alo[kt], bhi[i][kt], a1, 0, 0, 0);
                    a2 = __builtin_amdgcn_mfma_f32_16x16x32_bf16(ahi[kt], blo[i][kt], a2, 0, 0, 0);
                }
                const int n = ntg * 16 + r;
                if (lane < 16 && n < G3)
                    gates_sh[n] = a0[0] + a1[0] + a2[0] + bias[i];
            }
        }
        __syncthreads();

        // ---- phase 2: activations + h update
        if (j < HH) {
            const float ghr = gates_sh[j];
            const float ghz = gates_sh[HH + j];
            const float ghn = gates_sh[2 * HH + j];
            const float rg = fast_sigmoid(xr + ghr);
            const float zg = fast_sigmoid(xz + ghz);
            const float ng = fast_tanh(xn + rg * ghn);
            hj = (1.f - zg) * ng + zg * hj;
            hmax = fmaxf(hmax, hj);
            const unsigned short hb = f2bf_rne(hj);
            hhi_sh[j] = hb;
            hlo_sh[j] = f2bf_rne(hj - bf2f(hb));
            xr = xr_n; xz = xz_n; xn = xn_n;
        }
        __syncthreads();
        s = s_n;
    }
    if (j < HH) pool[(long)b * (2 * HH) + dir * HH + j] = hmax;
}

// ---------------- K4: out[b][o] = fc_b[o] + pool[b,:] . fc_w[o,:]
__global__ __launch_bounds__(256) void k4_fc(const float* __restrict__ pool,
                                             const float* __restrict__ fc_w,
                                             const float* __restrict__ fc_b,
                                             float* __restrict__ out) {
    const int b = blockIdx.x;
    __shared__ __align__(16) float p_sh[2 * HH];
    const int t = threadIdx.x;
    if (t < 2 * HH) p_sh[t] = pool[(long)b * (2 * HH) + t];
    __syncthreads();
    if (t < OUTD) {
        const float4* wr4 = (const float4*)(fc_w + (long)t * (2 * HH));
        const float4* p4 = (const float4*)p_sh;
        float a0 = 0.f, a1 = 0.f;
#pragma unroll
        for (int k = 0; k < 50; k += 2) {
            float4 w0 = wr4[k],   p0 = p4[k];
            float4 w1 = wr4[k+1], p1 = p4[k+1];
            a0 += w0.x*p0.x + w0.y*p0.y + w0.z*p0.z + w0.w*p0.w;
            a1 += w1.x*p1.x + w1.y*p1.y + w1.z*p1.z + w1.w*p1.w;
        }
        out[(long)b * OUTD + t] = fc_b[t] + a0 + a1;
    }
}

extern "C" void kernel_launch(void* const* d_in, const int* in_sizes, int n_in,
                              void* d_out, int out_size, void* d_ws, size_t ws_size,
                              hipStream_t stream) {
    const int*   tok    = (const int*)d_in[0];
    const float* emb    = (const float*)d_in[4];
    const float* w_lin  = (const float*)d_in[5];
    const float* b_lin  = (const float*)d_in[6];
    const float* w_ih_f = (const float*)d_in[7];
    const float* w_hh_f = (const float*)d_in[8];
    const float* b_ih_f = (const float*)d_in[9];
    const float* b_hh_f = (const float*)d_in[10];
    const float* w_ih_b = (const float*)d_in[11];
    const float* w_hh_b = (const float*)d_in[12];
    const float* b_ih_b = (const float*)d_in[13];
    const float* b_hh_b = (const float*)d_in[14];
    const float* fc_w   = (const float*)d_in[15];
    const float* fc_b   = (const float*)d_in[16];

    float* ws       = (float*)d_ws;
    float* tree_vec = ws;                                   // 12800*128
    float* gx       = tree_vec + (long)NTREE * CC;          // 2*12800*300
    float* pool     = gx + (long)2 * NTREE * G3;            // 64*200
    float* out      = (float*)d_out;

    k1_mfma<<<NTREE / K1_TPI, 256, 0, stream>>>(tok, emb, w_lin, b_lin, tree_vec);
    k2_mfma<<<(NTREE / 32) * 10, 256, 0, stream>>>(tree_vec, w_ih_f, b_ih_f, w_ih_b, b_ih_b, gx);
    k3_gru <<<2 * BB, 256, 0, stream>>>(gx, w_hh_f, b_hh_f, w_hh_b, b_hh_b, pool);
    k4_fc  <<<BB, 256, 0, stream>>>(pool, fc_w, fc_b, out);
}